// Round 4
// baseline (1094.552 us; speedup 1.0000x reference)
//
#include <hip/hip_runtime.h>
#include <cstdint>
#include <cstddef>

// FoldingBlock round 4.
// p1 = up(p); pdelta = p - down(p1); out = p1 + up(pdelta)
// BIG GEMMs (up-proj, hlg, x, f1): 256x256 tile, BK=32, 8 waves (2Mx4N),
//   4-slot LDS ring (128 KiB), depth-3 prefetch, counted vmcnt(8) (never 0
//   in steady state), ONE barrier per K-step, k-chunk-major LDS layout
//   (conflict-free ds_read_b128), setprio around MFMA cluster.
// SMALL GEMMs (mm, f2, down): round-3 proven 128x128 BK=64 double-buffer.
// g written pre-transposed from hlg epilogue (no transpose pass).

typedef unsigned short u16;
typedef __bf16 bf16x8 __attribute__((ext_vector_type(8)));
typedef float f32x4 __attribute__((ext_vector_type(4)));

__device__ __forceinline__ u16 f2bf(float f) {
    unsigned u = __builtin_bit_cast(unsigned, f);
    unsigned r = (u + 0x7fffu + ((u >> 16) & 1u)) >> 16;
    return (u16)r;
}
__device__ __forceinline__ float bf2f(u16 h) {
    unsigned u = ((unsigned)h) << 16;
    return __builtin_bit_cast(float, u);
}
__device__ __forceinline__ bf16x8 ldfrag(const u16* p) {
    return __builtin_bit_cast(bf16x8, *reinterpret_cast<const uint4*>(p));
}
__device__ __forceinline__ void gload16(const u16* g, u16* l) {
    __builtin_amdgcn_global_load_lds((__attribute__((address_space(1))) void*)g,
                                     (__attribute__((address_space(3))) void*)l,
                                     16, 0, 0);
}

// ---------------- BIG kernel: M=256 rows per batch, BN=256, BK=32 ----------
// Modes:
// 0 UP : A=p_bf rows&63 (K=512), B=WupT;  epi pts-rank2(EXf=W_up fp32)+bias+relu -> outB [256][512]
// 1 HLG: A=cat(p_bf rows&63, upout) K=1024, B=WhlgT[1536][1024];
//        epi bias+relu -> col<256:outB=h [256][256]; col<512:out1=l; col>=512:out2=gT [1024][256] (transposed)
// 3 X  : A=attn_bf K=256, B=gT per-batch (sB); epi += cat(EXf fp32 | EXb bf16, A1=upout) -> outB=x [256][1024]
// 4 F1 : A=x K=1024, B=Wf1T; epi bias+relu -> outB [256][512]
template<int MODE>
__global__ __launch_bounds__(512, 2)
void bg(const u16* __restrict__ A0, const u16* __restrict__ A1,
        const u16* __restrict__ Bt, const float* __restrict__ bias,
        const float* __restrict__ EXf, const u16* __restrict__ EXb,
        u16* __restrict__ outB, u16* __restrict__ out1, u16* __restrict__ out2,
        int K, long sB)
{
    // ring: 4 slots x (A 256x32 + B 256x32) bf16, k-chunk-major: [4 chunks][256 rows][8]
    __shared__ __align__(16) u16 As[4][256 * 32];
    __shared__ __align__(16) u16 Bs[4][256 * 32];

    const int b    = blockIdx.z;
    const int tid  = threadIdx.x;
    const int lane = tid & 63;
    const int w    = tid >> 6;            // 8 waves
    const int wr   = w >> 2;              // 0..1  (M half)
    const int wc   = w & 3;               // 0..3  (N quarter)
    const int wrow0 = wr * 128;
    const int wcol0 = wc * 64;
    const int gn0  = blockIdx.x * 256;
    const int lm   = lane & 15, hk = lane >> 4;

    const int NT = K / 32;

    auto stage = [&](int kt, int slot) {
        const int kb = kt * 32;
        #pragma unroll
        for (int t = 0; t < 2; ++t) {
            const int idx = tid + t * 512;          // 0..1023
            const int U   = idx >> 8;               // k-chunk 0..3
            const int row = idx & 255;
            const int k   = kb + U * 8;
            const u16* ga;
            if constexpr (MODE == 0) {
                ga = A0 + ((size_t)b << 15) + (size_t)(row & 63) * 512 + k;
            } else if constexpr (MODE == 1) {
                ga = (k < 512) ? A0 + ((size_t)b << 15) + (size_t)(row & 63) * 512 + k
                               : A1 + ((size_t)b << 17) + (size_t)row * 512 + (k - 512);
            } else if constexpr (MODE == 3) {
                ga = A0 + ((size_t)b << 16) + (size_t)row * 256 + k;
            } else { // 4
                ga = A0 + ((size_t)b << 18) + (size_t)row * 1024 + k;
            }
            gload16(ga, &As[slot][(size_t)(t * 512 + w * 64) * 8]);
        }
        #pragma unroll
        for (int t = 0; t < 2; ++t) {
            const int idx = tid + t * 512;
            const int U   = idx >> 8;
            const int row = idx & 255;
            const int k   = kb + U * 8;
            gload16(Bt + (size_t)b * sB + (size_t)(gn0 + row) * K + k,
                    &Bs[slot][(size_t)(t * 512 + w * 64) * 8]);
        }
    };

    f32x4 acc[8][4];
    #pragma unroll
    for (int i = 0; i < 8; ++i)
        #pragma unroll
        for (int j = 0; j < 4; ++j)
            acc[i][j] = (f32x4){0.f, 0.f, 0.f, 0.f};

    stage(0, 0);
    stage(1, 1);
    stage(2, 2);

    for (int kt = 0; kt < NT; ++kt) {
        const int s = kt & 3;
        const int rem = NT - 1 - kt;
        if (rem >= 2)      asm volatile("s_waitcnt vmcnt(8)" ::: "memory");
        else if (rem == 1) asm volatile("s_waitcnt vmcnt(4)" ::: "memory");
        else               asm volatile("s_waitcnt vmcnt(0)" ::: "memory");
        __builtin_amdgcn_s_barrier();
        asm volatile("" ::: "memory");

        // frag reads: k-chunk-major -> 16 consecutive 16B slots per hk group (conflict-free)
        bf16x8 af[8], bfr[4];
        #pragma unroll
        for (int i = 0; i < 8; ++i)
            af[i] = ldfrag(&As[s][(size_t)hk * 2048 + (size_t)(wrow0 + i * 16 + lm) * 8]);
        #pragma unroll
        for (int j = 0; j < 4; ++j)
            bfr[j] = ldfrag(&Bs[s][(size_t)hk * 2048 + (size_t)(wcol0 + j * 16 + lm) * 8]);

        if (kt + 3 < NT) stage(kt + 3, (kt + 3) & 3);

        __builtin_amdgcn_s_setprio(1);
        #pragma unroll
        for (int i = 0; i < 8; ++i)
            #pragma unroll
            for (int j = 0; j < 4; ++j)
                acc[i][j] = __builtin_amdgcn_mfma_f32_16x16x32_bf16(af[i], bfr[j], acc[i][j], 0, 0, 0);
        __builtin_amdgcn_s_setprio(0);
        asm volatile("" ::: "memory");
    }

    // ---- epilogue ----
    #pragma unroll
    for (int i = 0; i < 8; ++i) {
        const int rowb = wrow0 + i * 16 + hk * 4;
        #pragma unroll
        for (int j = 0; j < 4; ++j) {
            const int col = gn0 + wcol0 + j * 16 + lm;
            float v4[4];
            #pragma unroll
            for (int r = 0; r < 4; ++r) v4[r] = acc[i][j][r];

            if constexpr (MODE == 0) {
                #pragma unroll
                for (int r = 0; r < 4; ++r) {
                    const int row = rowb + r;
                    float v = v4[r];
                    const float px = -0.3f + 0.04f * (float)(row >> 4);
                    const float py = -0.3f + 0.04f * (float)(row & 15);
                    v += px * EXf[(size_t)512 * 512 + col] + py * EXf[(size_t)513 * 512 + col];
                    v = fmaxf(v + bias[col], 0.0f);
                    outB[((size_t)b << 17) + (size_t)row * 512 + col] = f2bf(v);
                }
            } else if constexpr (MODE == 1) {
                if (col < 512) {
                    #pragma unroll
                    for (int r = 0; r < 4; ++r) {
                        const int row = rowb + r;
                        float v = fmaxf(v4[r] + bias[col], 0.0f);
                        if (col < 256) outB[((size_t)b << 16) + (size_t)row * 256 + col] = f2bf(v);
                        else           out1[((size_t)b << 16) + (size_t)row * 256 + (col - 256)] = f2bf(v);
                    }
                } else {
                    ushort4 o;
                    o.x = f2bf(fmaxf(v4[0] + bias[col], 0.0f));
                    o.y = f2bf(fmaxf(v4[1] + bias[col], 0.0f));
                    o.z = f2bf(fmaxf(v4[2] + bias[col], 0.0f));
                    o.w = f2bf(fmaxf(v4[3] + bias[col], 0.0f));
                    // gT[col-512][rowb..rowb+3]  (transposed, 8B store)
                    *reinterpret_cast<ushort4*>(out2 + ((size_t)b << 18) +
                        (size_t)(col - 512) * 256 + rowb) = o;
                }
            } else if constexpr (MODE == 3) {
                #pragma unroll
                for (int r = 0; r < 4; ++r) {
                    const int row = rowb + r;
                    float v = v4[r];
                    float cv;
                    if (col < 512) {
                        const size_t ridx = ((size_t)b << 15) + (size_t)(row & 63) * 512 + col;
                        cv = EXf ? EXf[ridx] : bf2f(EXb[ridx]);
                    } else {
                        cv = bf2f(A1[((size_t)b << 17) + (size_t)row * 512 + (col - 512)]);
                    }
                    v += cv;
                    outB[((size_t)b << 18) + (size_t)row * 1024 + col] = f2bf(v);
                }
            } else { // 4
                #pragma unroll
                for (int r = 0; r < 4; ++r) {
                    const int row = rowb + r;
                    float v = fmaxf(v4[r] + bias[col], 0.0f);
                    outB[((size_t)b << 17) + (size_t)row * 512 + col] = f2bf(v);
                }
            }
        }
    }
}

// ---------------- SMALL kernel (round-3 proven): 128x128, BK=64 ------------
// Modes: 2 MM (logits=l@h^T), 5 F2, 6 DOWN (outF optional)
template<int MODE>
__global__ __launch_bounds__(256, 2)
void mg(const u16* __restrict__ A0, const u16* __restrict__ Bt,
        const float* __restrict__ bias, const float* __restrict__ EXf,
        float* __restrict__ outF, u16* __restrict__ outB,
        int K, long sB)
{
    constexpr int BK = 64;
    constexpr int UMASK = 7;

    __shared__ __align__(16) u16 As[2][128 * 64];
    __shared__ __align__(16) u16 Bs[2][128 * 64];

    const int b    = blockIdx.z;
    const int tid  = threadIdx.x;
    const int lane = tid & 63;
    const int w    = tid >> 6;
    const int wr   = w >> 1, wc = w & 1;
    const int wrow0 = wr * 64, wcol0 = wc * 64;
    const int gm0  = blockIdx.y * 128;
    const int gn0  = blockIdx.x * 128;
    const int lm   = lane & 15, hk = lane >> 4;
    const int NT = K / BK;

    auto stage = [&](int kt, int buf) {
        const int kb = kt * BK;
        #pragma unroll
        for (int t = 0; t < 4; ++t) {
            const int idx = tid + t * 256;
            const int row = idx >> 3, u = idx & UMASK;
            const int kk = kb + ((u ^ (row & UMASK)) << 3);
            const u16* ga;
            if constexpr (MODE == 2) {
                ga = A0 + ((size_t)b << 16) + (size_t)(gm0 + row) * 256 + kk;
            } else if constexpr (MODE == 5) {
                ga = A0 + ((size_t)b << 17) + (size_t)(gm0 + row) * 512 + kk;
            } else { // 6: reshape p1 [64][1024]
                int gr = gm0 + row; if (gr > 63) gr = 63;
                ga = A0 + ((size_t)b << 16) + (size_t)(gr * 4 + (kk >> 8)) * 256 + (kk & 255);
            }
            gload16(ga, &As[buf][(size_t)(w * 64 + t * 256) * 8]);
        }
        #pragma unroll
        for (int t = 0; t < 4; ++t) {
            const int idx = tid + t * 256;
            const int row = idx >> 3, u = idx & UMASK;
            const int kk = kb + ((u ^ (row & UMASK)) << 3);
            gload16(Bt + (size_t)b * sB + (size_t)(gn0 + row) * K + kk,
                    &Bs[buf][(size_t)(w * 64 + t * 256) * 8]);
        }
    };

    f32x4 acc[4][4];
    #pragma unroll
    for (int i = 0; i < 4; ++i)
        #pragma unroll
        for (int j = 0; j < 4; ++j)
            acc[i][j] = (f32x4){0.f, 0.f, 0.f, 0.f};

    stage(0, 0);
    if (NT > 1) stage(1, 1);

    for (int kt = 0; kt < NT; ++kt) {
        const int cur = kt & 1;
        if (kt == NT - 1) asm volatile("s_waitcnt vmcnt(0)" ::: "memory");
        else              asm volatile("s_waitcnt vmcnt(8)" ::: "memory");
        __builtin_amdgcn_s_barrier();
        asm volatile("" ::: "memory");

        #pragma unroll
        for (int ks = 0; ks < 2; ++ks) {
            bf16x8 af[4], bfr[4];
            #pragma unroll
            for (int i = 0; i < 4; ++i) {
                const int row = wrow0 + i * 16 + lm;
                af[i] = ldfrag(&As[cur][(size_t)row * BK + (((ks * 4 + hk) ^ (row & UMASK)) << 3)]);
            }
            #pragma unroll
            for (int j = 0; j < 4; ++j) {
                const int row = wcol0 + j * 16 + lm;
                bfr[j] = ldfrag(&Bs[cur][(size_t)row * BK + (((ks * 4 + hk) ^ (row & UMASK)) << 3)]);
            }
            __builtin_amdgcn_s_setprio(1);
            #pragma unroll
            for (int i = 0; i < 4; ++i)
                #pragma unroll
                for (int j = 0; j < 4; ++j)
                    acc[i][j] = __builtin_amdgcn_mfma_f32_16x16x32_bf16(af[i], bfr[j], acc[i][j], 0, 0, 0);
            __builtin_amdgcn_s_setprio(0);
        }

        asm volatile("" ::: "memory");
        __builtin_amdgcn_s_barrier();
        if (kt + 2 < NT) stage(kt + 2, cur);
    }

    #pragma unroll
    for (int i = 0; i < 4; ++i) {
        #pragma unroll
        for (int r = 0; r < 4; ++r) {
            const int row = gm0 + wrow0 + i * 16 + hk * 4 + r;
            if (MODE == 6 && row >= 64) continue;
            #pragma unroll
            for (int j = 0; j < 4; ++j) {
                const int col = gn0 + wcol0 + j * 16 + lm;
                float v = acc[i][j][r];
                if constexpr (MODE == 2) {
                    outF[((size_t)b << 16) + (size_t)row * 256 + col] = v;
                } else if constexpr (MODE == 5) {
                    v = fmaxf(v + bias[col], 0.0f);
                    const size_t oidx = ((size_t)b << 16) + (size_t)row * 256 + col;
                    if (EXf) v += EXf[oidx];
                    outF[oidx] = v;
                    if (outB) outB[oidx] = f2bf(v);
                } else { // 6
                    v = fmaxf(v + bias[col], 0.0f);
                    const size_t oidx = ((size_t)b << 15) + (size_t)row * 512 + col;
                    v = EXf[oidx] - v;
                    outB[oidx] = f2bf(v);
                }
            }
        }
    }
}

// ---------------- aux kernels ----------------
template<bool F32IN>
__global__ __launch_bounds__(256)
void transpose_k(const void* __restrict__ in_, u16* __restrict__ out, int R, int C)
{
    __shared__ float t[64][65];
    const size_t zo = (size_t)blockIdx.z * (size_t)R * C;
    const int c0 = blockIdx.x * 64, r0 = blockIdx.y * 64;
    const int x = threadIdx.x, y = threadIdx.y;
    #pragma unroll
    for (int i = 0; i < 16; ++i) {
        const int r = y * 16 + i;
        float v;
        if constexpr (F32IN) v = ((const float*)in_)[zo + (size_t)(r0 + r) * C + c0 + x];
        else                 v = bf2f(((const u16*)in_)[zo + (size_t)(r0 + r) * C + c0 + x]);
        t[r][x] = v;
    }
    __syncthreads();
    #pragma unroll
    for (int i = 0; i < 16; ++i) {
        const int c = y * 16 + i;
        out[zo + (size_t)(c0 + c) * R + r0 + x] = f2bf(t[x][c]);
    }
}

__global__ __launch_bounds__(256)
void cvt_k(const float* __restrict__ in, u16* __restrict__ out, int n4)
{
    int i = blockIdx.x * 256 + threadIdx.x;
    const int stride = gridDim.x * 256;
    for (; i < n4; i += stride) {
        float4 v = ((const float4*)in)[i];
        ushort4 o;
        o.x = f2bf(v.x); o.y = f2bf(v.y); o.z = f2bf(v.z); o.w = f2bf(v.w);
        ((ushort4*)out)[i] = o;
    }
}

__global__ __launch_bounds__(512)
void concat3_k(const float* __restrict__ a, const float* __restrict__ bb,
               const float* __restrict__ c, float* __restrict__ o)
{
    const int i = blockIdx.x * 512 + threadIdx.x;
    if (i < 256)       o[i] = a[i];
    else if (i < 512)  o[i] = bb[i - 256];
    else if (i < 1536) o[i] = c[i - 512];
}

__global__ __launch_bounds__(64)
void softmax_k(const float* __restrict__ logits, u16* __restrict__ attn)
{
    const size_t row = blockIdx.x;
    const float4 v = ((const float4*)(logits + row * 256))[threadIdx.x];
    float mx = fmaxf(fmaxf(v.x, v.y), fmaxf(v.z, v.w));
    #pragma unroll
    for (int o = 32; o > 0; o >>= 1) mx = fmaxf(mx, __shfl_xor(mx, o));
    float e0 = expf(v.x - mx), e1 = expf(v.y - mx), e2 = expf(v.z - mx), e3 = expf(v.w - mx);
    float s = e0 + e1 + e2 + e3;
    #pragma unroll
    for (int o = 32; o > 0; o >>= 1) s += __shfl_xor(s, o);
    const float inv = 1.0f / s;
    ushort4 o;
    o.x = f2bf(e0 * inv); o.y = f2bf(e1 * inv); o.z = f2bf(e2 * inv); o.w = f2bf(e3 * inv);
    ((ushort4*)(attn + row * 256))[threadIdx.x] = o;
}

extern "C" void kernel_launch(void* const* d_in, const int* in_sizes, int n_in,
                              void* d_out, int out_size, void* d_ws, size_t ws_size,
                              hipStream_t stream)
{
    const float* p      = (const float*)d_in[0];
    const float* W_up   = (const float*)d_in[1];
    const float* b_up   = (const float*)d_in[2];
    const float* Wh     = (const float*)d_in[3];
    const float* bh     = (const float*)d_in[4];
    const float* Wl     = (const float*)d_in[5];
    const float* bl     = (const float*)d_in[6];
    const float* Wg     = (const float*)d_in[7];
    const float* bg_    = (const float*)d_in[8];
    const float* Wf1    = (const float*)d_in[9];
    const float* bf1    = (const float*)d_in[10];
    const float* Wf2    = (const float*)d_in[11];
    const float* bf2v   = (const float*)d_in[12];
    const float* W_down = (const float*)d_in[13];
    const float* b_down = (const float*)d_in[14];

    const int B = in_sizes[0] / 32768;
    float* out = (float*)d_out;

    char* wsp = (char*)d_ws;
    auto alloc = [&](size_t bytes) -> char* {
        char* r = wsp; wsp += (bytes + 255) & ~(size_t)255; return r;
    };

    // ---- fixed buffers ----
    u16* WupT  = (u16*)alloc((size_t)512 * 512 * 2);
    u16* WhlgT = (u16*)alloc((size_t)1536 * 1024 * 2);
    u16* Wf1T  = (u16*)alloc((size_t)512 * 1024 * 2);
    u16* Wf2T  = (u16*)alloc((size_t)256 * 512 * 2);
    u16* WdT   = (u16*)alloc((size_t)512 * 1024 * 2);
    float* bias_hlg = (float*)alloc((size_t)1536 * 4);
    u16* pbf   = (u16*)alloc((size_t)B * 32768 * 2);

    const size_t fixed_used = (size_t)(wsp - (char*)d_ws);
    const size_t perB = 2162688;   // upout+gT+xb+h+l+attn+p1bf+pdbf+p1f
    int BC = B;
    while (BC > 1 && fixed_used + (size_t)BC * perB + 4096 > ws_size) BC >>= 1;

    u16* upout = (u16*)alloc((size_t)BC * 131072 * 2);
    u16* gT    = (u16*)alloc((size_t)BC * 262144 * 2);
    u16* xb    = (u16*)alloc((size_t)BC * 262144 * 2);
    u16* hb    = (u16*)alloc((size_t)BC * 65536 * 2);
    u16* lb    = (u16*)alloc((size_t)BC * 65536 * 2);
    u16* atb   = (u16*)alloc((size_t)BC * 65536 * 2);
    u16* p1bf  = (u16*)alloc((size_t)BC * 65536 * 2);
    u16* pdbf  = (u16*)alloc((size_t)BC * 32768 * 2);
    float* p1f = (float*)alloc((size_t)BC * 65536 * 4);
    float* lgt = (float*)xb;   // logits alias x-buffer (disjoint lifetimes)

    const dim3 tb(64, 4);
    // ---- startup (once) ----
    {
        int n4 = B * 8192;
        int nb = (n4 + 255) / 256; if (nb > 2048) nb = 2048;
        cvt_k<<<dim3(nb), dim3(256), 0, stream>>>(p, pbf, n4);
        transpose_k<true><<<dim3(8, 8, 1),  tb, 0, stream>>>(W_up, WupT, 512, 512);
        transpose_k<true><<<dim3(4, 16, 1), tb, 0, stream>>>(Wh, WhlgT, 1024, 256);
        transpose_k<true><<<dim3(4, 16, 1), tb, 0, stream>>>(Wl, WhlgT + (size_t)256 * 1024, 1024, 256);
        transpose_k<true><<<dim3(16, 16, 1),tb, 0, stream>>>(Wg, WhlgT + (size_t)512 * 1024, 1024, 1024);
        transpose_k<true><<<dim3(8, 16, 1), tb, 0, stream>>>(Wf1, Wf1T, 1024, 512);
        transpose_k<true><<<dim3(4, 8, 1),  tb, 0, stream>>>(Wf2, Wf2T, 512, 256);
        transpose_k<true><<<dim3(8, 16, 1), tb, 0, stream>>>(W_down, WdT, 1024, 512);
        concat3_k<<<dim3(3), dim3(512), 0, stream>>>(bh, bl, bg_, bias_hlg);
    }

    auto run_up = [&](const u16* pin_bf, const float* pin_f32, const u16* pin_ebf,
                      float* f2outF, u16* f2outB, const float* f2EXf, int bc) {
        bg<0><<<dim3(2, 1, bc), dim3(512), 0, stream>>>(
            pin_bf, nullptr, WupT, b_up, W_up, nullptr, upout, nullptr, nullptr, 512, 0);
        bg<1><<<dim3(6, 1, bc), dim3(512), 0, stream>>>(
            pin_bf, upout, WhlgT, bias_hlg, nullptr, nullptr, hb, lb, gT, 1024, 0);
        mg<2><<<dim3(2, 2, bc), dim3(256), 0, stream>>>(
            lb, hb, nullptr, nullptr, lgt, nullptr, 256, 65536);
        softmax_k<<<dim3(bc * 256), dim3(64), 0, stream>>>(lgt, atb);
        bg<3><<<dim3(4, 1, bc), dim3(512), 0, stream>>>(
            atb, upout, gT, nullptr, pin_f32, pin_ebf, xb, nullptr, nullptr, 256, 262144);
        bg<4><<<dim3(2, 1, bc), dim3(512), 0, stream>>>(
            xb, nullptr, Wf1T, bf1, nullptr, nullptr, upout, nullptr, nullptr, 1024, 0);
        mg<5><<<dim3(2, 2, bc), dim3(256), 0, stream>>>(
            upout, Wf2T, bf2v, f2EXf, f2outF, f2outB, 512, 0);
    };

    for (int b0 = 0; b0 < B; b0 += BC) {
        const int bc = (B - b0 < BC) ? (B - b0) : BC;
        const u16*   pin_bf  = pbf + (size_t)b0 * 32768;
        const float* pin_f32 = p   + (size_t)b0 * 32768;
        // up #1 -> p1 (fp32 + bf16)
        run_up(pin_bf, pin_f32, nullptr, p1f, p1bf, nullptr, bc);
        // pdelta = p - relu(reshape(p1) @ W_down + b)  (bf16 only)
        mg<6><<<dim3(4, 1, bc), dim3(256), 0, stream>>>(
            p1bf, WdT, b_down, pin_f32, nullptr, pdbf, 1024, 0);
        // up #2 -> d_out chunk, fused "+ p1"
        run_up(pdbf, nullptr, pdbf, out + (size_t)b0 * 65536, nullptr, p1f, bc);
    }
}

// Round 5
// 873.579 us; speedup vs baseline: 1.2530x; 1.2530x over previous
//
#include <hip/hip_runtime.h>
#include <cstdint>
#include <cstddef>

// FoldingBlock round 5: 8-phase-per-2-Ktile (4 phases/K-tile) 256x256 MFMA
// pipeline (m201 port) for the big GEMMs; proven SMALL kernel for the rest.
// p1 = up(p); pdelta = p - down(p1); out = p1 + up(pdelta)

typedef unsigned short u16;
typedef __bf16 bf16x8 __attribute__((ext_vector_type(8)));
typedef float f32x4 __attribute__((ext_vector_type(4)));

__device__ __forceinline__ u16 f2bf(float f) {
    unsigned u = __builtin_bit_cast(unsigned, f);
    unsigned r = (u + 0x7fffu + ((u >> 16) & 1u)) >> 16;
    return (u16)r;
}
__device__ __forceinline__ float bf2f(u16 h) {
    unsigned u = ((unsigned)h) << 16;
    return __builtin_bit_cast(float, u);
}
__device__ __forceinline__ bf16x8 ldfrag(const u16* p) {
    return __builtin_bit_cast(bf16x8, *reinterpret_cast<const uint4*>(p));
}
__device__ __forceinline__ void gload16(const u16* g, u16* l) {
    __builtin_amdgcn_global_load_lds((__attribute__((address_space(1))) void*)g,
                                     (__attribute__((address_space(3))) void*)l,
                                     16, 0, 0);
}

#define FENCE asm volatile("" ::: "memory")
#define BAR() do { FENCE; __builtin_amdgcn_s_barrier(); FENCE; } while (0)

// ================= BIG pipelined kernel: BM=256/batch, BN=256, BK=64 =======
// grid: (N/256, batches). 512 threads, 8 waves (2M x 4N), per-wave 128x64 out.
// LDS: 2 buffers x [8 k-units][256 rows][8 bf16] per matrix = 128 KiB.
// Per K-tile: 4 phases. Phase = {ds_read subtile; stage 2 loads; barrier;
//   16 MFMA (setprio-wrapped); barrier}. vmcnt(4) once per tile (phase 3).
// Modes: 0 UP, 1 HLG (h,l + gT transposed out), 3 X (per-batch B), 4 F1.
template<int MODE>
__global__ __launch_bounds__(512, 1)
void bp(const u16* __restrict__ A0, const u16* __restrict__ A1,
        const u16* __restrict__ Bt, const float* __restrict__ bias,
        const float* __restrict__ EXf, const u16* __restrict__ EXb,
        u16* __restrict__ outB, u16* __restrict__ out1, u16* __restrict__ out2,
        int K, long sB)
{
    __shared__ __align__(16) u16 As[2][16384];
    __shared__ __align__(16) u16 Bs[2][16384];

    const int b    = blockIdx.y;
    const int tid  = threadIdx.x;
    const int lane = tid & 63;
    const int w    = tid >> 6;
    const int wr   = w >> 2, wc = w & 3;
    const int wrow0 = wr * 128, wcol0 = wc * 64;
    const int gn0  = blockIdx.x * 256;
    const int lm   = lane & 15, hk = lane >> 4;
    const int NT   = K / 64;

    const int srow = tid & 255;
    const int su   = tid >> 8;

    auto stgA = [&](int kt, int buf, int rp) {
        const int kb = kt * 64;
        #pragma unroll
        for (int rr = 0; rr < 2; ++rr) {
            const int U = rp * 4 + rr * 2 + su;
            const int k = kb + U * 8;
            const u16* ga;
            if constexpr (MODE == 0) {
                ga = A0 + ((size_t)b << 15) + (size_t)(srow & 63) * 512 + k;
            } else if constexpr (MODE == 1) {
                ga = (k < 512) ? A0 + ((size_t)b << 15) + (size_t)(srow & 63) * 512 + k
                               : A1 + ((size_t)b << 17) + (size_t)srow * 512 + (k - 512);
            } else if constexpr (MODE == 3) {
                ga = A0 + ((size_t)b << 16) + (size_t)srow * 256 + k;
            } else { // 4
                ga = A0 + ((size_t)b << 18) + (size_t)srow * 1024 + k;
            }
            gload16(ga, &As[buf][(size_t)(U * 256 + srow) * 8]);
        }
    };
    auto stgB = [&](int kt, int buf, int rp) {
        const int kb = kt * 64;
        #pragma unroll
        for (int rr = 0; rr < 2; ++rr) {
            const int U = rp * 4 + rr * 2 + su;
            const int k = kb + U * 8;
            gload16(Bt + (size_t)b * sB + (size_t)(gn0 + srow) * K + k,
                    &Bs[buf][(size_t)(U * 256 + srow) * 8]);
        }
    };
    auto rdA = [&](int buf, int i, int ks) {
        const int row = wrow0 + i * 16 + lm;
        return ldfrag(&As[buf][(size_t)((ks * 4 + hk) * 256 + row) * 8]);
    };
    auto rdB = [&](int buf, int j, int ks) {
        const int row = wcol0 + j * 16 + lm;
        return ldfrag(&Bs[buf][(size_t)((ks * 4 + hk) * 256 + row) * 8]);
    };

    f32x4 acc[8][4];
    #pragma unroll
    for (int i = 0; i < 8; ++i)
        #pragma unroll
        for (int j = 0; j < 4; ++j)
            acc[i][j] = (f32x4){0.f, 0.f, 0.f, 0.f};

    // prologue: tile0 fully (8 loads), tile1 U0-3 halves (4 loads)
    stgA(0, 0, 0); stgA(0, 0, 1);
    stgB(0, 0, 0); stgB(0, 0, 1);
    stgA(1, 1, 0); stgB(1, 1, 0);
    asm volatile("s_waitcnt vmcnt(4)" ::: "memory");
    BAR();

    for (int t = 0; t < NT; ++t) {
        const int buf = t & 1, nx = buf ^ 1;
        bf16x8 aq[4], bq[4];

        // ---- phase 0: ks0, M-quadrant 0 (i 0-3) ----
        #pragma unroll
        for (int i = 0; i < 4; ++i) aq[i] = rdA(buf, i, 0);
        #pragma unroll
        for (int j = 0; j < 4; ++j) bq[j] = rdB(buf, j, 0);
        if (t + 1 < NT) stgA(t + 1, nx, 1);
        BAR();
        __builtin_amdgcn_s_setprio(1);
        #pragma unroll
        for (int i = 0; i < 4; ++i)
            #pragma unroll
            for (int j = 0; j < 4; ++j)
                acc[i][j] = __builtin_amdgcn_mfma_f32_16x16x32_bf16(aq[i], bq[j], acc[i][j], 0, 0, 0);
        __builtin_amdgcn_s_setprio(0);
        BAR();

        // ---- phase 1: ks0, M-quadrant 1 (i 4-7) ----
        #pragma unroll
        for (int i = 0; i < 4; ++i) aq[i] = rdA(buf, 4 + i, 0);
        if (t + 1 < NT) stgB(t + 1, nx, 1);
        BAR();
        __builtin_amdgcn_s_setprio(1);
        #pragma unroll
        for (int i = 0; i < 4; ++i)
            #pragma unroll
            for (int j = 0; j < 4; ++j)
                acc[4 + i][j] = __builtin_amdgcn_mfma_f32_16x16x32_bf16(aq[i], bq[j], acc[4 + i][j], 0, 0, 0);
        __builtin_amdgcn_s_setprio(0);
        BAR();

        // ---- phase 2: ks1, M-quadrant 0 ----
        #pragma unroll
        for (int i = 0; i < 4; ++i) aq[i] = rdA(buf, i, 1);
        #pragma unroll
        for (int j = 0; j < 4; ++j) bq[j] = rdB(buf, j, 1);
        if (t + 2 < NT) stgA(t + 2, buf, 0);
        BAR();
        __builtin_amdgcn_s_setprio(1);
        #pragma unroll
        for (int i = 0; i < 4; ++i)
            #pragma unroll
            for (int j = 0; j < 4; ++j)
                acc[i][j] = __builtin_amdgcn_mfma_f32_16x16x32_bf16(aq[i], bq[j], acc[i][j], 0, 0, 0);
        __builtin_amdgcn_s_setprio(0);
        BAR();

        // ---- phase 3: ks1, M-quadrant 1 ----
        #pragma unroll
        for (int i = 0; i < 4; ++i) aq[i] = rdA(buf, 4 + i, 1);
        if (t + 2 < NT) stgB(t + 2, buf, 0);
        if (t + 2 < NT) { asm volatile("s_waitcnt vmcnt(4)" ::: "memory"); }
        else            { asm volatile("s_waitcnt vmcnt(0)" ::: "memory"); }
        BAR();
        __builtin_amdgcn_s_setprio(1);
        #pragma unroll
        for (int i = 0; i < 4; ++i)
            #pragma unroll
            for (int j = 0; j < 4; ++j)
                acc[4 + i][j] = __builtin_amdgcn_mfma_f32_16x16x32_bf16(aq[i], bq[j], acc[4 + i][j], 0, 0, 0);
        __builtin_amdgcn_s_setprio(0);
        BAR();
    }

    // ---- epilogue ----
    #pragma unroll
    for (int i = 0; i < 8; ++i) {
        const int rowb = wrow0 + i * 16 + hk * 4;
        #pragma unroll
        for (int j = 0; j < 4; ++j) {
            const int col = gn0 + wcol0 + j * 16 + lm;
            float v4[4];
            #pragma unroll
            for (int r = 0; r < 4; ++r) v4[r] = acc[i][j][r];

            if constexpr (MODE == 0) {
                #pragma unroll
                for (int r = 0; r < 4; ++r) {
                    const int row = rowb + r;
                    float v = v4[r];
                    const float px = -0.3f + 0.04f * (float)(row >> 4);
                    const float py = -0.3f + 0.04f * (float)(row & 15);
                    v += px * EXf[(size_t)512 * 512 + col] + py * EXf[(size_t)513 * 512 + col];
                    v = fmaxf(v + bias[col], 0.0f);
                    outB[((size_t)b << 17) + (size_t)row * 512 + col] = f2bf(v);
                }
            } else if constexpr (MODE == 1) {
                if (col < 512) {
                    #pragma unroll
                    for (int r = 0; r < 4; ++r) {
                        const int row = rowb + r;
                        float v = fmaxf(v4[r] + bias[col], 0.0f);
                        if (col < 256) outB[((size_t)b << 16) + (size_t)row * 256 + col] = f2bf(v);
                        else           out1[((size_t)b << 16) + (size_t)row * 256 + (col - 256)] = f2bf(v);
                    }
                } else {
                    ushort4 o;
                    o.x = f2bf(fmaxf(v4[0] + bias[col], 0.0f));
                    o.y = f2bf(fmaxf(v4[1] + bias[col], 0.0f));
                    o.z = f2bf(fmaxf(v4[2] + bias[col], 0.0f));
                    o.w = f2bf(fmaxf(v4[3] + bias[col], 0.0f));
                    *reinterpret_cast<ushort4*>(out2 + ((size_t)b << 18) +
                        (size_t)(col - 512) * 256 + rowb) = o;
                }
            } else if constexpr (MODE == 3) {
                #pragma unroll
                for (int r = 0; r < 4; ++r) {
                    const int row = rowb + r;
                    float v = v4[r];
                    float cv;
                    if (col < 512) {
                        const size_t ridx = ((size_t)b << 15) + (size_t)(row & 63) * 512 + col;
                        cv = EXf ? EXf[ridx] : bf2f(EXb[ridx]);
                    } else {
                        cv = bf2f(A1[((size_t)b << 17) + (size_t)row * 512 + (col - 512)]);
                    }
                    v += cv;
                    outB[((size_t)b << 18) + (size_t)row * 1024 + col] = f2bf(v);
                }
            } else { // 4
                #pragma unroll
                for (int r = 0; r < 4; ++r) {
                    const int row = rowb + r;
                    float v = fmaxf(v4[r] + bias[col], 0.0f);
                    outB[((size_t)b << 17) + (size_t)row * 512 + col] = f2bf(v);
                }
            }
        }
    }
}

// ================ SMALL kernel (round-3/4 proven): 128x128, BK=64 ==========
// Modes: 2 MM (logits = l @ h^T), 5 F2 (+EXf residual, fp32+bf16 out), 6 DOWN
template<int MODE>
__global__ __launch_bounds__(256, 2)
void mg(const u16* __restrict__ A0, const u16* __restrict__ Bt,
        const float* __restrict__ bias, const float* __restrict__ EXf,
        float* __restrict__ outF, u16* __restrict__ outB,
        int K, long sB)
{
    constexpr int BK = 64;
    constexpr int UMASK = 7;

    __shared__ __align__(16) u16 As[2][128 * 64];
    __shared__ __align__(16) u16 Bs[2][128 * 64];

    const int b    = blockIdx.z;
    const int tid  = threadIdx.x;
    const int lane = tid & 63;
    const int w    = tid >> 6;
    const int wr   = w >> 1, wc = w & 1;
    const int wrow0 = wr * 64, wcol0 = wc * 64;
    const int gm0  = blockIdx.y * 128;
    const int gn0  = blockIdx.x * 128;
    const int lm   = lane & 15, hk = lane >> 4;
    const int NT = K / BK;

    auto stage = [&](int kt, int buf) {
        const int kb = kt * BK;
        #pragma unroll
        for (int t = 0; t < 4; ++t) {
            const int idx = tid + t * 256;
            const int row = idx >> 3, u = idx & UMASK;
            const int kk = kb + ((u ^ (row & UMASK)) << 3);
            const u16* ga;
            if constexpr (MODE == 2) {
                ga = A0 + ((size_t)b << 16) + (size_t)(gm0 + row) * 256 + kk;
            } else if constexpr (MODE == 5) {
                ga = A0 + ((size_t)b << 17) + (size_t)(gm0 + row) * 512 + kk;
            } else { // 6: reshape p1 [64][1024]
                int gr = gm0 + row; if (gr > 63) gr = 63;
                ga = A0 + ((size_t)b << 16) + (size_t)(gr * 4 + (kk >> 8)) * 256 + (kk & 255);
            }
            gload16(ga, &As[buf][(size_t)(w * 64 + t * 256) * 8]);
        }
        #pragma unroll
        for (int t = 0; t < 4; ++t) {
            const int idx = tid + t * 256;
            const int row = idx >> 3, u = idx & UMASK;
            const int kk = kb + ((u ^ (row & UMASK)) << 3);
            gload16(Bt + (size_t)b * sB + (size_t)(gn0 + row) * K + kk,
                    &Bs[buf][(size_t)(w * 64 + t * 256) * 8]);
        }
    };

    f32x4 acc[4][4];
    #pragma unroll
    for (int i = 0; i < 4; ++i)
        #pragma unroll
        for (int j = 0; j < 4; ++j)
            acc[i][j] = (f32x4){0.f, 0.f, 0.f, 0.f};

    stage(0, 0);
    if (NT > 1) stage(1, 1);

    for (int kt = 0; kt < NT; ++kt) {
        const int cur = kt & 1;
        if (kt == NT - 1) asm volatile("s_waitcnt vmcnt(0)" ::: "memory");
        else              asm volatile("s_waitcnt vmcnt(8)" ::: "memory");
        __builtin_amdgcn_s_barrier();
        FENCE;

        #pragma unroll
        for (int ks = 0; ks < 2; ++ks) {
            bf16x8 af[4], bfr[4];
            #pragma unroll
            for (int i = 0; i < 4; ++i) {
                const int row = wrow0 + i * 16 + lm;
                af[i] = ldfrag(&As[cur][(size_t)row * BK + (((ks * 4 + hk) ^ (row & UMASK)) << 3)]);
            }
            #pragma unroll
            for (int j = 0; j < 4; ++j) {
                const int row = wcol0 + j * 16 + lm;
                bfr[j] = ldfrag(&Bs[cur][(size_t)row * BK + (((ks * 4 + hk) ^ (row & UMASK)) << 3)]);
            }
            __builtin_amdgcn_s_setprio(1);
            #pragma unroll
            for (int i = 0; i < 4; ++i)
                #pragma unroll
                for (int j = 0; j < 4; ++j)
                    acc[i][j] = __builtin_amdgcn_mfma_f32_16x16x32_bf16(af[i], bfr[j], acc[i][j], 0, 0, 0);
            __builtin_amdgcn_s_setprio(0);
        }

        FENCE;
        __builtin_amdgcn_s_barrier();
        if (kt + 2 < NT) stage(kt + 2, cur);
    }

    #pragma unroll
    for (int i = 0; i < 4; ++i) {
        #pragma unroll
        for (int r = 0; r < 4; ++r) {
            const int row = gm0 + wrow0 + i * 16 + hk * 4 + r;
            if (MODE == 6 && row >= 64) continue;
            #pragma unroll
            for (int j = 0; j < 4; ++j) {
                const int col = gn0 + wcol0 + j * 16 + lm;
                float v = acc[i][j][r];
                if constexpr (MODE == 2) {
                    outF[((size_t)b << 16) + (size_t)row * 256 + col] = v;
                } else if constexpr (MODE == 5) {
                    v = fmaxf(v + bias[col], 0.0f);
                    const size_t oidx = ((size_t)b << 16) + (size_t)row * 256 + col;
                    if (EXf) v += EXf[oidx];
                    outF[oidx] = v;
                    if (outB) outB[oidx] = f2bf(v);
                } else { // 6
                    v = fmaxf(v + bias[col], 0.0f);
                    const size_t oidx = ((size_t)b << 15) + (size_t)row * 512 + col;
                    v = EXf[oidx] - v;
                    outB[oidx] = f2bf(v);
                }
            }
        }
    }
}

// ---------------- aux kernels ----------------
template<bool F32IN>
__global__ __launch_bounds__(256)
void transpose_k(const void* __restrict__ in_, u16* __restrict__ out, int R, int C)
{
    __shared__ float t[64][65];
    const size_t zo = (size_t)blockIdx.z * (size_t)R * C;
    const int c0 = blockIdx.x * 64, r0 = blockIdx.y * 64;
    const int x = threadIdx.x, y = threadIdx.y;
    #pragma unroll
    for (int i = 0; i < 16; ++i) {
        const int r = y * 16 + i;
        float v;
        if constexpr (F32IN) v = ((const float*)in_)[zo + (size_t)(r0 + r) * C + c0 + x];
        else                 v = bf2f(((const u16*)in_)[zo + (size_t)(r0 + r) * C + c0 + x]);
        t[r][x] = v;
    }
    __syncthreads();
    #pragma unroll
    for (int i = 0; i < 16; ++i) {
        const int c = y * 16 + i;
        out[zo + (size_t)(c0 + c) * R + r0 + x] = f2bf(t[x][c]);
    }
}

__global__ __launch_bounds__(256)
void cvt_k(const float* __restrict__ in, u16* __restrict__ out, int n4)
{
    int i = blockIdx.x * 256 + threadIdx.x;
    const int stride = gridDim.x * 256;
    for (; i < n4; i += stride) {
        float4 v = ((const float4*)in)[i];
        ushort4 o;
        o.x = f2bf(v.x); o.y = f2bf(v.y); o.z = f2bf(v.z); o.w = f2bf(v.w);
        ((ushort4*)out)[i] = o;
    }
}

__global__ __launch_bounds__(512)
void concat3_k(const float* __restrict__ a, const float* __restrict__ bb,
               const float* __restrict__ c, float* __restrict__ o)
{
    const int i = blockIdx.x * 512 + threadIdx.x;
    if (i < 256)       o[i] = a[i];
    else if (i < 512)  o[i] = bb[i - 256];
    else if (i < 1536) o[i] = c[i - 512];
}

__global__ __launch_bounds__(64)
void softmax_k(const float* __restrict__ logits, u16* __restrict__ attn)
{
    const size_t row = blockIdx.x;
    const float4 v = ((const float4*)(logits + row * 256))[threadIdx.x];
    float mx = fmaxf(fmaxf(v.x, v.y), fmaxf(v.z, v.w));
    #pragma unroll
    for (int o = 32; o > 0; o >>= 1) mx = fmaxf(mx, __shfl_xor(mx, o));
    float e0 = expf(v.x - mx), e1 = expf(v.y - mx), e2 = expf(v.z - mx), e3 = expf(v.w - mx);
    float s = e0 + e1 + e2 + e3;
    #pragma unroll
    for (int o = 32; o > 0; o >>= 1) s += __shfl_xor(s, o);
    const float inv = 1.0f / s;
    ushort4 o;
    o.x = f2bf(e0 * inv); o.y = f2bf(e1 * inv); o.z = f2bf(e2 * inv); o.w = f2bf(e3 * inv);
    ((ushort4*)(attn + row * 256))[threadIdx.x] = o;
}

extern "C" void kernel_launch(void* const* d_in, const int* in_sizes, int n_in,
                              void* d_out, int out_size, void* d_ws, size_t ws_size,
                              hipStream_t stream)
{
    const float* p      = (const float*)d_in[0];
    const float* W_up   = (const float*)d_in[1];
    const float* b_up   = (const float*)d_in[2];
    const float* Wh     = (const float*)d_in[3];
    const float* bh     = (const float*)d_in[4];
    const float* Wl     = (const float*)d_in[5];
    const float* bl     = (const float*)d_in[6];
    const float* Wg     = (const float*)d_in[7];
    const float* bg_    = (const float*)d_in[8];
    const float* Wf1    = (const float*)d_in[9];
    const float* bf1    = (const float*)d_in[10];
    const float* Wf2    = (const float*)d_in[11];
    const float* bf2v   = (const float*)d_in[12];
    const float* W_down = (const float*)d_in[13];
    const float* b_down = (const float*)d_in[14];

    const int B = in_sizes[0] / 32768;
    float* out = (float*)d_out;

    char* wsp = (char*)d_ws;
    auto alloc = [&](size_t bytes) -> char* {
        char* r = wsp; wsp += (bytes + 255) & ~(size_t)255; return r;
    };

    // ---- fixed buffers ----
    u16* WupT  = (u16*)alloc((size_t)512 * 512 * 2);
    u16* WhlgT = (u16*)alloc((size_t)1536 * 1024 * 2);
    u16* Wf1T  = (u16*)alloc((size_t)512 * 1024 * 2);
    u16* Wf2T  = (u16*)alloc((size_t)256 * 512 * 2);
    u16* WdT   = (u16*)alloc((size_t)512 * 1024 * 2);
    float* bias_hlg = (float*)alloc((size_t)1536 * 4);
    u16* pbf   = (u16*)alloc((size_t)B * 32768 * 2);

    const size_t fixed_used = (size_t)(wsp - (char*)d_ws);
    const size_t perB = 1903104;   // upout+gT+xb+h+l+attn+p1bf+pdbf (+pads)
    int BC = B;
    while (BC > 1 && fixed_used + (size_t)BC * perB + 4096 > ws_size) BC >>= 1;

    u16* upout = (u16*)alloc((size_t)BC * 131072 * 2);
    u16* gT    = (u16*)alloc((size_t)BC * 262144 * 2);
    u16* xb    = (u16*)alloc((size_t)BC * 262144 * 2);
    u16* hb    = (u16*)alloc((size_t)BC * 65536 * 2);
    u16* lb    = (u16*)alloc((size_t)BC * 65536 * 2);
    u16* atb   = (u16*)alloc((size_t)BC * 65536 * 2);
    u16* p1bf  = (u16*)alloc((size_t)BC * 65536 * 2);
    u16* pdbf  = (u16*)alloc((size_t)BC * 32768 * 2);
    float* lgt = (float*)xb;   // logits alias x-buffer (disjoint lifetimes)

    const dim3 tb(64, 4);
    // ---- startup (once) ----
    {
        int n4 = B * 8192;
        int nb = (n4 + 255) / 256; if (nb > 2048) nb = 2048;
        cvt_k<<<dim3(nb), dim3(256), 0, stream>>>(p, pbf, n4);
        transpose_k<true><<<dim3(8, 8, 1),  tb, 0, stream>>>(W_up, WupT, 512, 512);
        transpose_k<true><<<dim3(4, 16, 1), tb, 0, stream>>>(Wh, WhlgT, 1024, 256);
        transpose_k<true><<<dim3(4, 16, 1), tb, 0, stream>>>(Wl, WhlgT + (size_t)256 * 1024, 1024, 256);
        transpose_k<true><<<dim3(16, 16, 1),tb, 0, stream>>>(Wg, WhlgT + (size_t)512 * 1024, 1024, 1024);
        transpose_k<true><<<dim3(8, 16, 1), tb, 0, stream>>>(Wf1, Wf1T, 1024, 512);
        transpose_k<true><<<dim3(4, 8, 1),  tb, 0, stream>>>(Wf2, Wf2T, 512, 256);
        transpose_k<true><<<dim3(8, 16, 1), tb, 0, stream>>>(W_down, WdT, 1024, 512);
        concat3_k<<<dim3(3), dim3(512), 0, stream>>>(bh, bl, bg_, bias_hlg);
    }

    auto run_up = [&](const u16* pin_bf, const float* pin_f32, const u16* pin_ebf,
                      float* f2outF, u16* f2outB, const float* f2EXf, int bc) {
        bp<0><<<dim3(2, bc), dim3(512), 0, stream>>>(
            pin_bf, nullptr, WupT, b_up, W_up, nullptr, upout, nullptr, nullptr, 512, 0);
        bp<1><<<dim3(6, bc), dim3(512), 0, stream>>>(
            pin_bf, upout, WhlgT, bias_hlg, nullptr, nullptr, hb, lb, gT, 1024, 0);
        mg<2><<<dim3(2, 2, bc), dim3(256), 0, stream>>>(
            lb, hb, nullptr, nullptr, lgt, nullptr, 256, 65536);
        softmax_k<<<dim3(bc * 256), dim3(64), 0, stream>>>(lgt, atb);
        bp<3><<<dim3(4, bc), dim3(512), 0, stream>>>(
            atb, upout, gT, nullptr, pin_f32, pin_ebf, xb, nullptr, nullptr, 256, 262144);
        bp<4><<<dim3(2, bc), dim3(512), 0, stream>>>(
            xb, nullptr, Wf1T, bf1, nullptr, nullptr, upout, nullptr, nullptr, 1024, 0);
        mg<5><<<dim3(2, 2, bc), dim3(256), 0, stream>>>(
            upout, Wf2T, bf2v, f2EXf, f2outF, f2outB, 512, 0);
    };

    for (int b0 = 0; b0 < B; b0 += BC) {
        const int bc = (B - b0 < BC) ? (B - b0) : BC;
        const u16*   pin_bf  = pbf + (size_t)b0 * 32768;
        const float* pin_f32 = p   + (size_t)b0 * 32768;
        float* outc = out + (size_t)b0 * 65536;
        // up #1 -> p1: fp32 directly into d_out, bf16 copy for down()
        run_up(pin_bf, pin_f32, nullptr, outc, p1bf, nullptr, bc);
        // pdelta = p - relu(reshape(p1) @ W_down + b)  (bf16)
        mg<6><<<dim3(4, 1, bc), dim3(256), 0, stream>>>(
            p1bf, WdT, b_down, pin_f32, nullptr, pdbf, 1024, 0);
        // up #2 -> d_out chunk, read-modify-write "+ p1"
        run_up(pdbf, nullptr, pdbf, outc, nullptr, outc, bc);
    }
}

// Round 6
// 868.998 us; speedup vs baseline: 1.2596x; 1.0053x over previous
//
#include <hip/hip_runtime.h>
#include <cstdint>
#include <cstddef>

// FoldingBlock round 6: round-5 4-phase 256x256 MFMA pipeline + hoisted
// addressing (per-thread global bases, uniform per-tile offsets, LDS base +
// literal offsets). Schedule/barriers/vmcnt identical to round 5 (passed).
// p1 = up(p); pdelta = p - down(p1); out = p1 + up(pdelta)

typedef unsigned short u16;
typedef __bf16 bf16x8 __attribute__((ext_vector_type(8)));
typedef float f32x4 __attribute__((ext_vector_type(4)));

__device__ __forceinline__ u16 f2bf(float f) {
    unsigned u = __builtin_bit_cast(unsigned, f);
    unsigned r = (u + 0x7fffu + ((u >> 16) & 1u)) >> 16;
    return (u16)r;
}
__device__ __forceinline__ float bf2f(u16 h) {
    unsigned u = ((unsigned)h) << 16;
    return __builtin_bit_cast(float, u);
}
__device__ __forceinline__ bf16x8 ldfrag(const u16* p) {
    return __builtin_bit_cast(bf16x8, *reinterpret_cast<const uint4*>(p));
}
__device__ __forceinline__ void gload16(const u16* g, u16* l) {
    __builtin_amdgcn_global_load_lds((__attribute__((address_space(1))) void*)g,
                                     (__attribute__((address_space(3))) void*)l,
                                     16, 0, 0);
}

#define FENCE asm volatile("" ::: "memory")
#define BAR() do { FENCE; __builtin_amdgcn_s_barrier(); FENCE; } while (0)

// ================= BIG pipelined kernel: BM=256/batch, BN=256, BK=64 =======
// grid: (N/256, batches). 512 threads, 8 waves (2M x 4N), per-wave 128x64 out.
// LDS: 2 buffers x [8 k-units][256 rows][8 bf16] per matrix = 128 KiB.
// 4 phases per K-tile; 2 staging loads per phase; vmcnt(4) once per tile.
// Modes: 0 UP, 1 HLG (h,l + gT transposed out), 3 X (per-batch B), 4 F1.
template<int MODE>
__global__ __launch_bounds__(512, 1)
void bp(const u16* __restrict__ A0, const u16* __restrict__ A1,
        const u16* __restrict__ Bt, const float* __restrict__ bias,
        const float* __restrict__ EXf, const u16* __restrict__ EXb,
        u16* __restrict__ outB, u16* __restrict__ out1, u16* __restrict__ out2,
        int K, long sB)
{
    __shared__ __align__(16) u16 As[2][16384];
    __shared__ __align__(16) u16 Bs[2][16384];

    const int b    = blockIdx.y;
    const int tid  = threadIdx.x;
    const int lane = tid & 63;
    const int w    = tid >> 6;
    const int wr   = w >> 2, wc = w & 3;
    const int wrow0 = wr * 128, wcol0 = wc * 64;
    const int gn0  = blockIdx.x * 256;
    const int lm   = lane & 15, hk = lane >> 4;
    const int NT   = K / 64;

    const int srow = tid & 255;   // row this thread stages
    const int su   = tid >> 8;    // 0/1 -> k element offset su*8

    // ---- hoisted per-thread staging bases (element pointers at kt=0) ----
    const u16* gA0;
    const u16* gA1 = nullptr;
    if constexpr (MODE == 0) {
        gA0 = A0 + ((size_t)b << 15) + (size_t)(srow & 63) * 512 + su * 8;
    } else if constexpr (MODE == 1) {
        gA0 = A0 + ((size_t)b << 15) + (size_t)(srow & 63) * 512 + su * 8;
        gA1 = A1 + ((size_t)b << 17) + (size_t)srow * 512 + su * 8;
    } else if constexpr (MODE == 3) {
        gA0 = A0 + ((size_t)b << 16) + (size_t)srow * 256 + su * 8;
    } else { // 4
        gA0 = A0 + ((size_t)b << 18) + (size_t)srow * 1024 + su * 8;
    }
    const u16* gB0 = Bt + (size_t)b * sB + (size_t)(gn0 + srow) * K + su * 8;

    // LDS staging dst base: (su*256 + srow)*8 ; +rp*8192 ; +rr*4096 ; +buf*16384
    u16* dA = &As[0][(size_t)(su * 256 + srow) * 8];
    u16* dB = &Bs[0][(size_t)(su * 256 + srow) * 8];

    // stage(kt, buf, rp): 2 loads, k = kt*64 + rp*32 + rr*16 + su*8
    auto stgA = [&](int kt, int buf, int rp) {
        const u16* g;
        if constexpr (MODE == 1) g = (kt < 8) ? (gA0 + kt * 64) : (gA1 + (kt - 8) * 64);
        else                     g = gA0 + kt * 64;
        u16* d = dA + buf * 16384 + rp * 8192;
        gload16(g + rp * 32,      d);
        gload16(g + rp * 32 + 16, d + 4096);
    };
    auto stgB = [&](int kt, int buf, int rp) {
        const u16* g = gB0 + kt * 64 + rp * 32;
        u16* d = dB + buf * 16384 + rp * 8192;
        gload16(g,      d);
        gload16(g + 16, d + 4096);
    };

    // ---- hoisted frag-read bases: frag(i,ks,buf) = base + buf*16384 + ks*8192 + i*128
    const u16* rA = &As[0][(size_t)(hk * 256 + wrow0 + lm) * 8];
    const u16* rB = &Bs[0][(size_t)(hk * 256 + wcol0 + lm) * 8];

    f32x4 acc[8][4];
    #pragma unroll
    for (int i = 0; i < 8; ++i)
        #pragma unroll
        for (int j = 0; j < 4; ++j)
            acc[i][j] = (f32x4){0.f, 0.f, 0.f, 0.f};

    // prologue: tile0 fully (8 loads), tile1 first halves (4 loads)
    stgA(0, 0, 0); stgA(0, 0, 1);
    stgB(0, 0, 0); stgB(0, 0, 1);
    stgA(1, 1, 0); stgB(1, 1, 0);
    asm volatile("s_waitcnt vmcnt(4)" ::: "memory");
    BAR();

    for (int t = 0; t < NT; ++t) {
        const int buf = t & 1, nx = buf ^ 1;
        const u16* a  = rA + buf * 16384;
        const u16* bb = rB + buf * 16384;
        bf16x8 aq[4], bq[4];

        // ---- phase 0: ks0, M-quadrant 0 (i 0-3) ----
        #pragma unroll
        for (int i = 0; i < 4; ++i) aq[i] = ldfrag(a + i * 128);
        #pragma unroll
        for (int j = 0; j < 4; ++j) bq[j] = ldfrag(bb + j * 128);
        if (t + 1 < NT) stgA(t + 1, nx, 1);
        BAR();
        __builtin_amdgcn_s_setprio(1);
        #pragma unroll
        for (int i = 0; i < 4; ++i)
            #pragma unroll
            for (int j = 0; j < 4; ++j)
                acc[i][j] = __builtin_amdgcn_mfma_f32_16x16x32_bf16(aq[i], bq[j], acc[i][j], 0, 0, 0);
        __builtin_amdgcn_s_setprio(0);
        BAR();

        // ---- phase 1: ks0, M-quadrant 1 (i 4-7), reuse bq ----
        #pragma unroll
        for (int i = 0; i < 4; ++i) aq[i] = ldfrag(a + (4 + i) * 128);
        if (t + 1 < NT) stgB(t + 1, nx, 1);
        BAR();
        __builtin_amdgcn_s_setprio(1);
        #pragma unroll
        for (int i = 0; i < 4; ++i)
            #pragma unroll
            for (int j = 0; j < 4; ++j)
                acc[4 + i][j] = __builtin_amdgcn_mfma_f32_16x16x32_bf16(aq[i], bq[j], acc[4 + i][j], 0, 0, 0);
        __builtin_amdgcn_s_setprio(0);
        BAR();

        // ---- phase 2: ks1, M-quadrant 0 ----
        #pragma unroll
        for (int i = 0; i < 4; ++i) aq[i] = ldfrag(a + 8192 + i * 128);
        #pragma unroll
        for (int j = 0; j < 4; ++j) bq[j] = ldfrag(bb + 8192 + j * 128);
        if (t + 2 < NT) stgA(t + 2, buf, 0);
        BAR();
        __builtin_amdgcn_s_setprio(1);
        #pragma unroll
        for (int i = 0; i < 4; ++i)
            #pragma unroll
            for (int j = 0; j < 4; ++j)
                acc[i][j] = __builtin_amdgcn_mfma_f32_16x16x32_bf16(aq[i], bq[j], acc[i][j], 0, 0, 0);
        __builtin_amdgcn_s_setprio(0);
        BAR();

        // ---- phase 3: ks1, M-quadrant 1 ----
        #pragma unroll
        for (int i = 0; i < 4; ++i) aq[i] = ldfrag(a + 8192 + (4 + i) * 128);
        if (t + 2 < NT) stgB(t + 2, buf, 0);
        if (t + 2 < NT) { asm volatile("s_waitcnt vmcnt(4)" ::: "memory"); }
        else            { asm volatile("s_waitcnt vmcnt(0)" ::: "memory"); }
        BAR();
        __builtin_amdgcn_s_setprio(1);
        #pragma unroll
        for (int i = 0; i < 4; ++i)
            #pragma unroll
            for (int j = 0; j < 4; ++j)
                acc[4 + i][j] = __builtin_amdgcn_mfma_f32_16x16x32_bf16(aq[i], bq[j], acc[4 + i][j], 0, 0, 0);
        __builtin_amdgcn_s_setprio(0);
        BAR();
    }

    // ---- epilogue ----
    #pragma unroll
    for (int i = 0; i < 8; ++i) {
        const int rowb = wrow0 + i * 16 + hk * 4;
        #pragma unroll
        for (int j = 0; j < 4; ++j) {
            const int col = gn0 + wcol0 + j * 16 + lm;
            float v4[4];
            #pragma unroll
            for (int r = 0; r < 4; ++r) v4[r] = acc[i][j][r];

            if constexpr (MODE == 0) {
                #pragma unroll
                for (int r = 0; r < 4; ++r) {
                    const int row = rowb + r;
                    float v = v4[r];
                    const float px = -0.3f + 0.04f * (float)(row >> 4);
                    const float py = -0.3f + 0.04f * (float)(row & 15);
                    v += px * EXf[(size_t)512 * 512 + col] + py * EXf[(size_t)513 * 512 + col];
                    v = fmaxf(v + bias[col], 0.0f);
                    outB[((size_t)b << 17) + (size_t)row * 512 + col] = f2bf(v);
                }
            } else if constexpr (MODE == 1) {
                if (col < 512) {
                    #pragma unroll
                    for (int r = 0; r < 4; ++r) {
                        const int row = rowb + r;
                        float v = fmaxf(v4[r] + bias[col], 0.0f);
                        if (col < 256) outB[((size_t)b << 16) + (size_t)row * 256 + col] = f2bf(v);
                        else           out1[((size_t)b << 16) + (size_t)row * 256 + (col - 256)] = f2bf(v);
                    }
                } else {
                    ushort4 o;
                    o.x = f2bf(fmaxf(v4[0] + bias[col], 0.0f));
                    o.y = f2bf(fmaxf(v4[1] + bias[col], 0.0f));
                    o.z = f2bf(fmaxf(v4[2] + bias[col], 0.0f));
                    o.w = f2bf(fmaxf(v4[3] + bias[col], 0.0f));
                    *reinterpret_cast<ushort4*>(out2 + ((size_t)b << 18) +
                        (size_t)(col - 512) * 256 + rowb) = o;
                }
            } else if constexpr (MODE == 3) {
                #pragma unroll
                for (int r = 0; r < 4; ++r) {
                    const int row = rowb + r;
                    float v = v4[r];
                    float cv;
                    if (col < 512) {
                        const size_t ridx = ((size_t)b << 15) + (size_t)(row & 63) * 512 + col;
                        cv = EXf ? EXf[ridx] : bf2f(EXb[ridx]);
                    } else {
                        cv = bf2f(A1[((size_t)b << 17) + (size_t)row * 512 + (col - 512)]);
                    }
                    v += cv;
                    outB[((size_t)b << 18) + (size_t)row * 1024 + col] = f2bf(v);
                }
            } else { // 4
                #pragma unroll
                for (int r = 0; r < 4; ++r) {
                    const int row = rowb + r;
                    float v = fmaxf(v4[r] + bias[col], 0.0f);
                    outB[((size_t)b << 17) + (size_t)row * 512 + col] = f2bf(v);
                }
            }
        }
    }
}

// ================ SMALL kernel (round-3/4/5 proven): 128x128, BK=64 ========
// Modes: 2 MM (logits = l @ h^T), 5 F2 (+EXf residual, fp32+bf16 out), 6 DOWN
template<int MODE>
__global__ __launch_bounds__(256, 2)
void mg(const u16* __restrict__ A0, const u16* __restrict__ Bt,
        const float* __restrict__ bias, const float* __restrict__ EXf,
        float* __restrict__ outF, u16* __restrict__ outB,
        int K, long sB)
{
    constexpr int BK = 64;
    constexpr int UMASK = 7;

    __shared__ __align__(16) u16 As[2][128 * 64];
    __shared__ __align__(16) u16 Bs[2][128 * 64];

    const int b    = blockIdx.z;
    const int tid  = threadIdx.x;
    const int lane = tid & 63;
    const int w    = tid >> 6;
    const int wr   = w >> 1, wc = w & 1;
    const int wrow0 = wr * 64, wcol0 = wc * 64;
    const int gm0  = blockIdx.y * 128;
    const int gn0  = blockIdx.x * 128;
    const int lm   = lane & 15, hk = lane >> 4;
    const int NT = K / BK;

    auto stage = [&](int kt, int buf) {
        const int kb = kt * BK;
        #pragma unroll
        for (int t = 0; t < 4; ++t) {
            const int idx = tid + t * 256;
            const int row = idx >> 3, u = idx & UMASK;
            const int kk = kb + ((u ^ (row & UMASK)) << 3);
            const u16* ga;
            if constexpr (MODE == 2) {
                ga = A0 + ((size_t)b << 16) + (size_t)(gm0 + row) * 256 + kk;
            } else if constexpr (MODE == 5) {
                ga = A0 + ((size_t)b << 17) + (size_t)(gm0 + row) * 512 + kk;
            } else { // 6: reshape p1 [64][1024]
                int gr = gm0 + row; if (gr > 63) gr = 63;
                ga = A0 + ((size_t)b << 16) + (size_t)(gr * 4 + (kk >> 8)) * 256 + (kk & 255);
            }
            gload16(ga, &As[buf][(size_t)(w * 64 + t * 256) * 8]);
        }
        #pragma unroll
        for (int t = 0; t < 4; ++t) {
            const int idx = tid + t * 256;
            const int row = idx >> 3, u = idx & UMASK;
            const int kk = kb + ((u ^ (row & UMASK)) << 3);
            gload16(Bt + (size_t)b * sB + (size_t)(gn0 + row) * K + kk,
                    &Bs[buf][(size_t)(w * 64 + t * 256) * 8]);
        }
    };

    f32x4 acc[4][4];
    #pragma unroll
    for (int i = 0; i < 4; ++i)
        #pragma unroll
        for (int j = 0; j < 4; ++j)
            acc[i][j] = (f32x4){0.f, 0.f, 0.f, 0.f};

    stage(0, 0);
    if (NT > 1) stage(1, 1);

    for (int kt = 0; kt < NT; ++kt) {
        const int cur = kt & 1;
        if (kt == NT - 1) asm volatile("s_waitcnt vmcnt(0)" ::: "memory");
        else              asm volatile("s_waitcnt vmcnt(8)" ::: "memory");
        __builtin_amdgcn_s_barrier();
        FENCE;

        #pragma unroll
        for (int ks = 0; ks < 2; ++ks) {
            bf16x8 af[4], bfr[4];
            #pragma unroll
            for (int i = 0; i < 4; ++i) {
                const int row = wrow0 + i * 16 + lm;
                af[i] = ldfrag(&As[cur][(size_t)row * BK + (((ks * 4 + hk) ^ (row & UMASK)) << 3)]);
            }
            #pragma unroll
            for (int j = 0; j < 4; ++j) {
                const int row = wcol0 + j * 16 + lm;
                bfr[j] = ldfrag(&Bs[cur][(size_t)row * BK + (((ks * 4 + hk) ^ (row & UMASK)) << 3)]);
            }
            __builtin_amdgcn_s_setprio(1);
            #pragma unroll
            for (int i = 0; i < 4; ++i)
                #pragma unroll
                for (int j = 0; j < 4; ++j)
                    acc[i][j] = __builtin_amdgcn_mfma_f32_16x16x32_bf16(af[i], bfr[j], acc[i][j], 0, 0, 0);
            __builtin_amdgcn_s_setprio(0);
        }

        FENCE;
        __builtin_amdgcn_s_barrier();
        if (kt + 2 < NT) stage(kt + 2, cur);
    }

    #pragma unroll
    for (int i = 0; i < 4; ++i) {
        #pragma unroll
        for (int r = 0; r < 4; ++r) {
            const int row = gm0 + wrow0 + i * 16 + hk * 4 + r;
            if (MODE == 6 && row >= 64) continue;
            #pragma unroll
            for (int j = 0; j < 4; ++j) {
                const int col = gn0 + wcol0 + j * 16 + lm;
                float v = acc[i][j][r];
                if constexpr (MODE == 2) {
                    outF[((size_t)b << 16) + (size_t)row * 256 + col] = v;
                } else if constexpr (MODE == 5) {
                    v = fmaxf(v + bias[col], 0.0f);
                    const size_t oidx = ((size_t)b << 16) + (size_t)row * 256 + col;
                    if (EXf) v += EXf[oidx];
                    outF[oidx] = v;
                    if (outB) outB[oidx] = f2bf(v);
                } else { // 6
                    v = fmaxf(v + bias[col], 0.0f);
                    const size_t oidx = ((size_t)b << 15) + (size_t)row * 512 + col;
                    v = EXf[oidx] - v;
                    outB[oidx] = f2bf(v);
                }
            }
        }
    }
}

// ---------------- aux kernels ----------------
template<bool F32IN>
__global__ __launch_bounds__(256)
void transpose_k(const void* __restrict__ in_, u16* __restrict__ out, int R, int C)
{
    __shared__ float t[64][65];
    const size_t zo = (size_t)blockIdx.z * (size_t)R * C;
    const int c0 = blockIdx.x * 64, r0 = blockIdx.y * 64;
    const int x = threadIdx.x, y = threadIdx.y;
    #pragma unroll
    for (int i = 0; i < 16; ++i) {
        const int r = y * 16 + i;
        float v;
        if constexpr (F32IN) v = ((const float*)in_)[zo + (size_t)(r0 + r) * C + c0 + x];
        else                 v = bf2f(((const u16*)in_)[zo + (size_t)(r0 + r) * C + c0 + x]);
        t[r][x] = v;
    }
    __syncthreads();
    #pragma unroll
    for (int i = 0; i < 16; ++i) {
        const int c = y * 16 + i;
        out[zo + (size_t)(c0 + c) * R + r0 + x] = f2bf(t[x][c]);
    }
}

__global__ __launch_bounds__(256)
void cvt_k(const float* __restrict__ in, u16* __restrict__ out, int n4)
{
    int i = blockIdx.x * 256 + threadIdx.x;
    const int stride = gridDim.x * 256;
    for (; i < n4; i += stride) {
        float4 v = ((const float4*)in)[i];
        ushort4 o;
        o.x = f2bf(v.x); o.y = f2bf(v.y); o.z = f2bf(v.z); o.w = f2bf(v.w);
        ((ushort4*)out)[i] = o;
    }
}

__global__ __launch_bounds__(512)
void concat3_k(const float* __restrict__ a, const float* __restrict__ bb,
               const float* __restrict__ c, float* __restrict__ o)
{
    const int i = blockIdx.x * 512 + threadIdx.x;
    if (i < 256)       o[i] = a[i];
    else if (i < 512)  o[i] = bb[i - 256];
    else if (i < 1536) o[i] = c[i - 512];
}

__global__ __launch_bounds__(64)
void softmax_k(const float* __restrict__ logits, u16* __restrict__ attn)
{
    const size_t row = blockIdx.x;
    const float4 v = ((const float4*)(logits + row * 256))[threadIdx.x];
    float mx = fmaxf(fmaxf(v.x, v.y), fmaxf(v.z, v.w));
    #pragma unroll
    for (int o = 32; o > 0; o >>= 1) mx = fmaxf(mx, __shfl_xor(mx, o));
    float e0 = expf(v.x - mx), e1 = expf(v.y - mx), e2 = expf(v.z - mx), e3 = expf(v.w - mx);
    float s = e0 + e1 + e2 + e3;
    #pragma unroll
    for (int o = 32; o > 0; o >>= 1) s += __shfl_xor(s, o);
    const float inv = 1.0f / s;
    ushort4 o;
    o.x = f2bf(e0 * inv); o.y = f2bf(e1 * inv); o.z = f2bf(e2 * inv); o.w = f2bf(e3 * inv);
    ((ushort4*)(attn + row * 256))[threadIdx.x] = o;
}

extern "C" void kernel_launch(void* const* d_in, const int* in_sizes, int n_in,
                              void* d_out, int out_size, void* d_ws, size_t ws_size,
                              hipStream_t stream)
{
    const float* p      = (const float*)d_in[0];
    const float* W_up   = (const float*)d_in[1];
    const float* b_up   = (const float*)d_in[2];
    const float* Wh     = (const float*)d_in[3];
    const float* bh     = (const float*)d_in[4];
    const float* Wl     = (const float*)d_in[5];
    const float* bl     = (const float*)d_in[6];
    const float* Wg     = (const float*)d_in[7];
    const float* bg_    = (const float*)d_in[8];
    const float* Wf1    = (const float*)d_in[9];
    const float* bf1    = (const float*)d_in[10];
    const float* Wf2    = (const float*)d_in[11];
    const float* bf2v   = (const float*)d_in[12];
    const float* W_down = (const float*)d_in[13];
    const float* b_down = (const float*)d_in[14];

    const int B = in_sizes[0] / 32768;
    float* out = (float*)d_out;

    char* wsp = (char*)d_ws;
    auto alloc = [&](size_t bytes) -> char* {
        char* r = wsp; wsp += (bytes + 255) & ~(size_t)255; return r;
    };

    // ---- fixed buffers ----
    u16* WupT  = (u16*)alloc((size_t)512 * 512 * 2);
    u16* WhlgT = (u16*)alloc((size_t)1536 * 1024 * 2);
    u16* Wf1T  = (u16*)alloc((size_t)512 * 1024 * 2);
    u16* Wf2T  = (u16*)alloc((size_t)256 * 512 * 2);
    u16* WdT   = (u16*)alloc((size_t)512 * 1024 * 2);
    float* bias_hlg = (float*)alloc((size_t)1536 * 4);
    u16* pbf   = (u16*)alloc((size_t)B * 32768 * 2);

    const size_t fixed_used = (size_t)(wsp - (char*)d_ws);
    const size_t perB = 1903104;   // upout+gT+xb+h+l+attn+p1bf+pdbf (+pads)
    int BC = B;
    while (BC > 1 && fixed_used + (size_t)BC * perB + 4096 > ws_size) BC >>= 1;

    u16* upout = (u16*)alloc((size_t)BC * 131072 * 2);
    u16* gT    = (u16*)alloc((size_t)BC * 262144 * 2);
    u16* xb    = (u16*)alloc((size_t)BC * 262144 * 2);
    u16* hb    = (u16*)alloc((size_t)BC * 65536 * 2);
    u16* lb    = (u16*)alloc((size_t)BC * 65536 * 2);
    u16* atb   = (u16*)alloc((size_t)BC * 65536 * 2);
    u16* p1bf  = (u16*)alloc((size_t)BC * 65536 * 2);
    u16* pdbf  = (u16*)alloc((size_t)BC * 32768 * 2);
    float* lgt = (float*)xb;   // logits alias x-buffer (disjoint lifetimes)

    const dim3 tb(64, 4);
    // ---- startup (once) ----
    {
        int n4 = B * 8192;
        int nb = (n4 + 255) / 256; if (nb > 2048) nb = 2048;
        cvt_k<<<dim3(nb), dim3(256), 0, stream>>>(p, pbf, n4);
        transpose_k<true><<<dim3(8, 8, 1),  tb, 0, stream>>>(W_up, WupT, 512, 512);
        transpose_k<true><<<dim3(4, 16, 1), tb, 0, stream>>>(Wh, WhlgT, 1024, 256);
        transpose_k<true><<<dim3(4, 16, 1), tb, 0, stream>>>(Wl, WhlgT + (size_t)256 * 1024, 1024, 256);
        transpose_k<true><<<dim3(16, 16, 1),tb, 0, stream>>>(Wg, WhlgT + (size_t)512 * 1024, 1024, 1024);
        transpose_k<true><<<dim3(8, 16, 1), tb, 0, stream>>>(Wf1, Wf1T, 1024, 512);
        transpose_k<true><<<dim3(4, 8, 1),  tb, 0, stream>>>(Wf2, Wf2T, 512, 256);
        transpose_k<true><<<dim3(8, 16, 1), tb, 0, stream>>>(W_down, WdT, 1024, 512);
        concat3_k<<<dim3(3), dim3(512), 0, stream>>>(bh, bl, bg_, bias_hlg);
    }

    auto run_up = [&](const u16* pin_bf, const float* pin_f32, const u16* pin_ebf,
                      float* f2outF, u16* f2outB, const float* f2EXf, int bc) {
        bp<0><<<dim3(2, bc), dim3(512), 0, stream>>>(
            pin_bf, nullptr, WupT, b_up, W_up, nullptr, upout, nullptr, nullptr, 512, 0);
        bp<1><<<dim3(6, bc), dim3(512), 0, stream>>>(
            pin_bf, upout, WhlgT, bias_hlg, nullptr, nullptr, hb, lb, gT, 1024, 0);
        mg<2><<<dim3(2, 2, bc), dim3(256), 0, stream>>>(
            lb, hb, nullptr, nullptr, lgt, nullptr, 256, 65536);
        softmax_k<<<dim3(bc * 256), dim3(64), 0, stream>>>(lgt, atb);
        bp<3><<<dim3(4, bc), dim3(512), 0, stream>>>(
            atb, upout, gT, nullptr, pin_f32, pin_ebf, xb, nullptr, nullptr, 256, 262144);
        bp<4><<<dim3(2, bc), dim3(512), 0, stream>>>(
            xb, nullptr, Wf1T, bf1, nullptr, nullptr, upout, nullptr, nullptr, 1024, 0);
        mg<5><<<dim3(2, 2, bc), dim3(256), 0, stream>>>(
            upout, Wf2T, bf2v, f2EXf, f2outF, f2outB, 512, 0);
    };

    for (int b0 = 0; b0 < B; b0 += BC) {
        const int bc = (B - b0 < BC) ? (B - b0) : BC;
        const u16*   pin_bf  = pbf + (size_t)b0 * 32768;
        const float* pin_f32 = p   + (size_t)b0 * 32768;
        float* outc = out + (size_t)b0 * 65536;
        // up #1 -> p1: fp32 directly into d_out, bf16 copy for down()
        run_up(pin_bf, pin_f32, nullptr, outc, p1bf, nullptr, bc);
        // pdelta = p - relu(reshape(p1) @ W_down + b)  (bf16)
        mg<6><<<dim3(4, 1, bc), dim3(256), 0, stream>>>(
            p1bf, WdT, b_down, pin_f32, nullptr, pdbf, 1024, 0);
        // up #2 -> d_out chunk, read-modify-write "+ p1"
        run_up(pdbf, nullptr, pdbf, outc, nullptr, outc, bc);
    }
}